// Round 1
// 130.497 us; speedup vs baseline: 1.0346x; 1.0346x over previous
//
#include <hip/hip_runtime.h>
#include <math.h>

// Problem constants (from reference setup_inputs)
#define BB 16
#define CC 85
#define HH 128
#define WW 128
#define NGT 64
#define HW (HH * WW)          // 16384
#define NC (CC - 5)           // 80
#define NCH 81                // channels 4..84 (obj + 80 cls)
#define NPART (BB * NCH)      // 1296 dense partial sums
#define NSLOT (NPART + 3 * BB) // 1344 tagged partials total

// Tag marking a published partial. d_ws is POISONED (not zeroed) by the
// harness each iteration, so a zero-init counter is unusable; instead every
// partial is a single 64-bit atomic store of (MAGIC<<32 | float_bits). The
// finisher block polls tags; the value rides in the same atomic word, so no
// release/acquire fencing is needed for cross-XCD visibility.
#define MAGIC 0xA5C3193Fu

// ws layout (as uint64 tagged slots):
//   [0 .. NPART)              : dense per-slice softplus sums (slot = b*81 + (c-4))
//   [NPART + 0*BB .. +1*BB)   : per-batch box-loss partials
//   [NPART + 1*BB .. +2*BB)   : per-batch gathered-obj partials (to subtract)
//   [NPART + 2*BB .. +3*BB)   : per-batch gathered-cls partials (to subtract)

__device__ __forceinline__ float softplus_f(float x) {
    // logaddexp(x,0) = max(x,0) + log1p(exp(-|x|)); exp(-|x|) in (0,1] so no
    // cancellation; ~1e-7 rel error, and the final means divide by 16384 / 1.3M.
    float ax = fabsf(x);
    float e = __expf(-ax);
    return fmaxf(x, 0.0f) + __logf(1.0f + e);
}

__device__ __forceinline__ void publish(unsigned long long* T, int slot, float v) {
    unsigned long long pk =
        ((unsigned long long)MAGIC << 32) | (unsigned long long)__float_as_uint(v);
    __hip_atomic_store(T + slot, pk, __ATOMIC_RELAXED, __HIP_MEMORY_SCOPE_AGENT);
}

// Single fused kernel. Grid: NPART + BB + 1 blocks x 256 threads.
//   blocks [0, NPART)        : dense softplus sum over one (b, c) channel slice
//   blocks [NPART, +BB)      : GT gather + IoU + set-dedup for one batch
//   block  NPART+BB (last)   : finisher — polls all 1344 tagged partials, then
//                              performs the final reduction (bit-identical to
//                              the old reduce_kernel) and writes out[0].
// The finisher is last in dispatch order so most tags are ready when it spins;
// no other block waits on it, so there is no deadlock hazard. All 1313 blocks
// are co-resident (~21 waves/CU), so the dense path saturates HBM regardless.
__global__ __launch_bounds__(256) void fused_kernel(const float* __restrict__ preds,
                                                    const float* __restrict__ tgt,
                                                    float* __restrict__ ws,
                                                    float* __restrict__ out) {
    const int bk = blockIdx.x;
    unsigned long long* T = (unsigned long long*)ws;

    if (bk < NPART) {
        // ---- dense path: 16384 elems = 256 threads x 16 float4 ----
        const int b = bk / NCH;
        const int c = 4 + (bk - b * NCH);
        const float4* p = (const float4*)(preds + ((size_t)(b * CC + c) * HW));

        float s = 0.0f;
        #pragma unroll
        for (int k = 0; k < 16; ++k) {
            float4 v = p[threadIdx.x + (k << 8)];
            s += softplus_f(v.x) + softplus_f(v.y) + softplus_f(v.z) + softplus_f(v.w);
        }

        #pragma unroll
        for (int off = 32; off > 0; off >>= 1) s += __shfl_down(s, off, 64);

        __shared__ float wsum[4];
        const int lane = threadIdx.x & 63;
        const int wv = threadIdx.x >> 6;
        if (lane == 0) wsum[wv] = s;
        __syncthreads();
        if (threadIdx.x == 0)
            publish(T, bk, wsum[0] + wsum[1] + wsum[2] + wsum[3]);
    } else if (bk < NPART + BB) {
        // ---- GT path: one batch, one GT per lane of wave 0 ----
        const int b = bk - NPART;
        const int n = threadIdx.x;
        __shared__ int s_idx[NGT];
        __shared__ int s_cls[NGT];

        float box = 0.0f, sub_o = 0.0f, sub_c = 0.0f;
        int idx = 0, cls = 0;
        float px = 0, py = 0, pw = 0, ph = 0, pobj = 0, pcls = 0;
        float cx = 0, cy = 0, w = 0, h = 0;

        if (n < NGT) {
            const float* t = tgt + ((size_t)(b * NGT + n)) * 5;
            cls = (int)t[0];
            cx = t[1]; cy = t[2]; w = t[3]; h = t[4];
            const int gi = (int)(cx * (float)WW);
            const int gj = (int)(cy * (float)HH);
            idx = gj * WW + gi;
            s_idx[n] = idx;
            s_cls[n] = cls;
            // issue scattered gathers early; latency overlaps the dedup barrier
            const float* pb = preds + (size_t)b * CC * HW + idx;
            px   = pb[0 * HW];
            py   = pb[1 * HW];
            pw   = pb[2 * HW];
            ph   = pb[3 * HW];
            pobj = pb[4 * HW];
            pcls = pb[(5 + cls) * HW];
        }
        __syncthreads();

        if (n < NGT) {
            // boxes exactly as the reference computes them
            const float p0 = px - pw * 0.5f, p1 = py - ph * 0.5f;
            const float p2 = px + pw * 0.5f, p3 = py + ph * 0.5f;
            const float g0 = (cx - w * 0.5f) * WW, g1 = (cy - h * 0.5f) * HH;
            const float g2 = (cx + w * 0.5f) * WW, g3 = (cy + h * 0.5f) * HH;

            const float ix1 = fmaxf(p0, g0), iy1 = fmaxf(p1, g1);
            const float ix2 = fminf(p2, g2), iy2 = fminf(p3, g3);
            const float inter = fmaxf(ix2 - ix1, 0.0f) * fmaxf(iy2 - iy1, 0.0f);
            const float a1 = (p2 - p0) * (p3 - p1);
            const float a2 = (g2 - g0) * (g3 - g1);
            const float iou = inter / (a1 + a2 - inter + 1e-7f);
            box = 1.0f - iou;

            // set semantics: a cell counts once (obj); a (cell,cls) pair once (cls)
            bool dup_o = false, dup_c = false;
            for (int m = 0; m < n; ++m) {
                if (s_idx[m] == idx) {
                    dup_o = true;
                    if (s_cls[m] == cls) dup_c = true;
                }
            }
            sub_o = dup_o ? 0.0f : pobj;
            sub_c = dup_c ? 0.0f : pcls;
        }

        if (n < 64) {   // wave 0 only
            #pragma unroll
            for (int off = 32; off > 0; off >>= 1) {
                box   += __shfl_down(box,   off, 64);
                sub_o += __shfl_down(sub_o, off, 64);
                sub_c += __shfl_down(sub_c, off, 64);
            }
            if (n == 0) {
                publish(T, NPART + 0 * BB + b, box);
                publish(T, NPART + 1 * BB + b, sub_o);
                publish(T, NPART + 2 * BB + b, sub_c);
            }
        }
    } else {
        // ---- finisher: poll all tagged partials, then reduce (same order as
        //      the old reduce_kernel → bit-identical result) ----
        const int tid = threadIdx.x;
        __shared__ float s_val[NSLOT];

        for (int k = tid; k < NSLOT; k += 256) {
            unsigned long long v;
            do {
                v = __hip_atomic_load(T + k, __ATOMIC_RELAXED, __HIP_MEMORY_SCOPE_AGENT);
            } while ((unsigned)(v >> 32) != MAGIC);
            s_val[k] = __uint_as_float((unsigned)(v & 0xFFFFFFFFull));
        }
        __syncthreads();

        double obj = 0.0, cls = 0.0;
        for (int k = tid; k < NPART; k += 256) {
            double v = (double)s_val[k];
            if (k % NCH == 0) obj += v; else cls += v;   // c==4 slots are obj
        }
        float box = 0.0f, sub_o = 0.0f, sub_c = 0.0f;
        if (tid < BB) {
            box   = s_val[NPART + 0 * BB + tid];
            sub_o = s_val[NPART + 1 * BB + tid];
            sub_c = s_val[NPART + 2 * BB + tid];
        }

        __shared__ double so[256], sc[256];
        __shared__ float sb[256], sso[256], ssc[256];
        so[tid] = obj; sc[tid] = cls; sb[tid] = box; sso[tid] = sub_o; ssc[tid] = sub_c;
        __syncthreads();
        for (int s = 128; s > 0; s >>= 1) {
            if (tid < s) {
                so[tid] += so[tid + s];
                sc[tid] += sc[tid + s];
                sb[tid] += sb[tid + s];
                sso[tid] += sso[tid + s];
                ssc[tid] += ssc[tid + s];
            }
            __syncthreads();
        }
        if (tid == 0) {
            double o = (so[0] - (double)sso[0]) / (double)HW;
            double c = (sc[0] - (double)ssc[0]) / ((double)HW * (double)NC);
            out[0] = (float)(0.05 * (double)sb[0] + 1.0 * o + 0.5 * c);
        }
    }
}

extern "C" void kernel_launch(void* const* d_in, const int* in_sizes, int n_in,
                              void* d_out, int out_size, void* d_ws, size_t ws_size,
                              hipStream_t stream) {
    const float* preds = (const float*)d_in[0];
    const float* targets = (const float*)d_in[1];
    float* out = (float*)d_out;
    float* ws = (float*)d_ws;

    fused_kernel<<<NPART + BB + 1, 256, 0, stream>>>(preds, targets, ws, out);
}